// Round 1
// baseline (624.101 us; speedup 1.0000x reference)
//
#include <hip/hip_runtime.h>

#define N_NODES 8192
#define N_EDGES 262144
#define D 256
#define ADJ_WORDS 256   // 8192 bits per row / 32
#define STATS_BLOCKS 64

// ---------------- adjacency build: set-semantics via bitmask ----------------
__global__ void build_adj(const int* __restrict__ ei, unsigned* __restrict__ adj) {
    int i = blockIdx.x * blockDim.x + threadIdx.x;
    int r, c;
    if (i < N_EDGES) {
        r = ei[i];              // edge_index[0][i]
        c = ei[N_EDGES + i];    // edge_index[1][i]
    } else if (i < N_EDGES + N_NODES) {
        r = i - N_EDGES;        // self loop
        c = r;
    } else {
        return;
    }
    atomicOr(&adj[r * ADJ_WORDS + (c >> 5)], 1u << (c & 31));
}

// ---------------- degree -> dinv = deg^-0.5 ----------------
__global__ __launch_bounds__(256) void compute_dinv(const unsigned* __restrict__ adj,
                                                    float* __restrict__ dinv) {
    int n = blockIdx.x;
    int cnt = __popc(adj[n * ADJ_WORDS + threadIdx.x]);
    for (int off = 32; off; off >>= 1) cnt += __shfl_down(cnt, off, 64);
    __shared__ int s[4];
    if ((threadIdx.x & 63) == 0) s[threadIdx.x >> 6] = cnt;
    __syncthreads();
    if (threadIdx.x == 0) {
        int deg = s[0] + s[1] + s[2] + s[3];
        dinv[n] = deg > 0 ? rsqrtf((float)deg) : 0.0f;
    }
}

// ---------------- H = X @ W^T + b   (fp32, 64x64 tile, 4x4 micro) ----------------
__global__ __launch_bounds__(256) void gemm_bias(const float* __restrict__ X,
                                                 const float* __restrict__ W,
                                                 const float* __restrict__ bias,
                                                 float* __restrict__ H) {
    __shared__ float Xs[16][65];  // [k][m], +1 pad
    __shared__ float Ws[16][65];  // [k][n]
    const int bm = blockIdx.y * 64, bn = blockIdx.x * 64;
    const int tid = threadIdx.x;
    const int tx = tid & 15, ty = tid >> 4;   // tx -> n (4 cols), ty -> m (4 rows)
    float acc[4][4] = {};
    for (int k0 = 0; k0 < D; k0 += 16) {
        #pragma unroll
        for (int i = 0; i < 4; i++) {
            int e = tid + 256 * i;
            int row = e >> 4, kk = e & 15;
            Xs[kk][row] = X[(size_t)(bm + row) * D + k0 + kk];
            Ws[kk][row] = W[(size_t)(bn + row) * D + k0 + kk];
        }
        __syncthreads();
        #pragma unroll
        for (int kk = 0; kk < 16; kk++) {
            float a[4], b[4];
            #pragma unroll
            for (int i = 0; i < 4; i++) a[i] = Xs[kk][ty * 4 + i];
            #pragma unroll
            for (int j = 0; j < 4; j++) b[j] = Ws[kk][tx * 4 + j];
            #pragma unroll
            for (int i = 0; i < 4; i++)
                #pragma unroll
                for (int j = 0; j < 4; j++)
                    acc[i][j] += a[i] * b[j];
        }
        __syncthreads();
    }
    #pragma unroll
    for (int i = 0; i < 4; i++) {
        int m = bm + ty * 4 + i;
        #pragma unroll
        for (int j = 0; j < 4; j++) {
            int n = bn + tx * 4 + j;
            H[(size_t)m * D + n] = acc[i][j] + bias[n];
        }
    }
}

// ---------------- Out[r,:] = dinv[r] * sum_{c in adj[r]} dinv[c] * H[c,:] ----------------
__global__ __launch_bounds__(256) void aggregate(const unsigned* __restrict__ adj,
                                                 const float* __restrict__ dinv,
                                                 const float* __restrict__ H,
                                                 float* __restrict__ Out) {
    const int r = blockIdx.x;
    __shared__ unsigned mask[ADJ_WORDS];
    mask[threadIdx.x] = adj[r * ADJ_WORDS + threadIdx.x];
    __syncthreads();
    const int d = threadIdx.x;
    float acc = 0.0f;
    for (int w = 0; w < ADJ_WORDS; w++) {
        unsigned bits = mask[w];
        while (bits) {
            int b = __ffs(bits) - 1;
            bits &= bits - 1;
            int c = (w << 5) + b;
            acc += dinv[c] * H[(size_t)c * D + d];
        }
    }
    Out[(size_t)r * D + d] = dinv[r] * acc;
}

// ---------------- BN stats: stage 1 (partials, no atomics / no zero-init) ----------------
__global__ __launch_bounds__(256) void bn_stats1(const float* __restrict__ H,
                                                 float* __restrict__ psum,
                                                 float* __restrict__ psumsq) {
    const int d = threadIdx.x;
    float s = 0.0f, ss = 0.0f;
    for (int r = blockIdx.x; r < N_NODES; r += gridDim.x) {
        float v = H[(size_t)r * D + d];
        s += v;
        ss += v * v;
    }
    psum[blockIdx.x * D + d] = s;
    psumsq[blockIdx.x * D + d] = ss;
}

// ---------------- BN stats: stage 2 (finalize scale/shift) ----------------
__global__ __launch_bounds__(256) void bn_stats2(const float* __restrict__ psum,
                                                 const float* __restrict__ psumsq,
                                                 const float* __restrict__ g,
                                                 const float* __restrict__ be,
                                                 float* __restrict__ scale,
                                                 float* __restrict__ shift) {
    const int d = threadIdx.x;
    float s = 0.0f, ss = 0.0f;
    for (int i = 0; i < STATS_BLOCKS; i++) {
        s += psum[i * D + d];
        ss += psumsq[i * D + d];
    }
    float mu = s * (1.0f / N_NODES);
    float var = ss * (1.0f / N_NODES) - mu * mu;
    float rstd = rsqrtf(var + 1e-5f);
    float sc = g[d] * rstd;
    scale[d] = sc;
    shift[d] = be[d] - mu * sc;
}

// ---------------- BN apply (+ optional ReLU) ----------------
template <bool RELU>
__global__ __launch_bounds__(256) void bn_apply(const float* __restrict__ H,
                                                const float* __restrict__ scale,
                                                const float* __restrict__ shift,
                                                float* __restrict__ Out) {
    int i = blockIdx.x * blockDim.x + threadIdx.x;
    int d = i & (D - 1);
    float v = fmaf(H[i], scale[d], shift[d]);
    if (RELU) v = fmaxf(v, 0.0f);
    Out[i] = v;
}

extern "C" void kernel_launch(void* const* d_in, const int* in_sizes, int n_in,
                              void* d_out, int out_size, void* d_ws, size_t ws_size,
                              hipStream_t stream) {
    const float* x  = (const float*)d_in[0];
    const int*   ei = (const int*)d_in[1];
    const float* W1 = (const float*)d_in[2];
    const float* b1 = (const float*)d_in[3];
    const float* W2 = (const float*)d_in[4];
    const float* b2 = (const float*)d_in[5];
    const float* W3 = (const float*)d_in[6];
    const float* b3 = (const float*)d_in[7];
    const float* g1 = (const float*)d_in[8];
    const float* be1 = (const float*)d_in[9];
    const float* g2 = (const float*)d_in[10];
    const float* be2 = (const float*)d_in[11];
    const float* g3 = (const float*)d_in[12];
    const float* be3 = (const float*)d_in[13];

    char* ws = (char*)d_ws;
    unsigned* adj   = (unsigned*)ws;                               // 8 MB
    float*    dinv  = (float*)(ws + (8 << 20));                    // 32 KB
    float*    psum  = (float*)(ws + (8 << 20) + (64 << 10));       // 64 KB
    float*    psumsq= (float*)(ws + (8 << 20) + (128 << 10));      // 64 KB
    float*    scale = (float*)(ws + (8 << 20) + (192 << 10));      // 1 KB
    float*    shift = (float*)(ws + (8 << 20) + (196 << 10));      // 1 KB
    float*    bufA  = (float*)(ws + (9 << 20));                    // 8 MB
    float*    bufB  = (float*)(ws + (17 << 20));                   // 8 MB

    // adjacency bitmask must start from zero every call (ws is poisoned 0xAA)
    hipMemsetAsync(adj, 0, (size_t)N_NODES * ADJ_WORDS * sizeof(unsigned), stream);

    {
        int total = N_EDGES + N_NODES;
        build_adj<<<(total + 255) / 256, 256, 0, stream>>>(ei, adj);
    }
    compute_dinv<<<N_NODES, 256, 0, stream>>>(adj, dinv);

    dim3 ggrid(D / 64, N_NODES / 64);

    // ---- Layer 1: x -> bufA (gemm) -> bufB (agg) -> bufA (bn+relu)
    gemm_bias<<<ggrid, 256, 0, stream>>>(x, W1, b1, bufA);
    aggregate<<<N_NODES, 256, 0, stream>>>(adj, dinv, bufA, bufB);
    bn_stats1<<<STATS_BLOCKS, 256, 0, stream>>>(bufB, psum, psumsq);
    bn_stats2<<<1, 256, 0, stream>>>(psum, psumsq, g1, be1, scale, shift);
    bn_apply<true><<<N_NODES * D / 256, 256, 0, stream>>>(bufB, scale, shift, bufA);

    // ---- Layer 2: bufA -> bufB (gemm) -> bufA (agg) -> bufB (bn+relu)
    gemm_bias<<<ggrid, 256, 0, stream>>>(bufA, W2, b2, bufB);
    aggregate<<<N_NODES, 256, 0, stream>>>(adj, dinv, bufB, bufA);
    bn_stats1<<<STATS_BLOCKS, 256, 0, stream>>>(bufA, psum, psumsq);
    bn_stats2<<<1, 256, 0, stream>>>(psum, psumsq, g2, be2, scale, shift);
    bn_apply<true><<<N_NODES * D / 256, 256, 0, stream>>>(bufA, scale, shift, bufB);

    // ---- Layer 3: bufB -> bufA (gemm) -> bufB (agg) -> d_out (bn, no relu)
    gemm_bias<<<ggrid, 256, 0, stream>>>(bufB, W3, b3, bufA);
    aggregate<<<N_NODES, 256, 0, stream>>>(adj, dinv, bufA, bufB);
    bn_stats1<<<STATS_BLOCKS, 256, 0, stream>>>(bufB, psum, psumsq);
    bn_stats2<<<1, 256, 0, stream>>>(psum, psumsq, g3, be3, scale, shift);
    bn_apply<false><<<N_NODES * D / 256, 256, 0, stream>>>(bufB, scale, shift, (float*)d_out);
}

// Round 2
// 344.315 us; speedup vs baseline: 1.8126x; 1.8126x over previous
//
#include <hip/hip_runtime.h>

#define N_NODES 8192
#define N_EDGES 262144
#define D 256
#define ADJ_WORDS 256     // 8192 bits per row / 32
#define MAX_DEG 128       // Poisson(33): P(deg>128) ~ 1e-40
#define STATS_BLOCKS 256

// ---------------- adjacency build: set-semantics via bitmask ----------------
__global__ void build_adj(const int* __restrict__ ei, unsigned* __restrict__ adj) {
    int i = blockIdx.x * blockDim.x + threadIdx.x;
    int r, c;
    if (i < N_EDGES) {
        r = ei[i];              // edge_index[0][i]
        c = ei[N_EDGES + i];    // edge_index[1][i]
    } else if (i < N_EDGES + N_NODES) {
        r = i - N_EDGES;        // self loop
        c = r;
    } else {
        return;
    }
    atomicOr(&adj[r * ADJ_WORDS + (c >> 5)], 1u << (c & 31));
}

// ---------------- degree -> dinv = deg^-0.5 ----------------
__global__ __launch_bounds__(256) void compute_dinv(const unsigned* __restrict__ adj,
                                                    float* __restrict__ dinv) {
    int n = blockIdx.x;
    int cnt = __popc(adj[n * ADJ_WORDS + threadIdx.x]);
    for (int off = 32; off; off >>= 1) cnt += __shfl_down(cnt, off, 64);
    __shared__ int s[4];
    if ((threadIdx.x & 63) == 0) s[threadIdx.x >> 6] = cnt;
    __syncthreads();
    if (threadIdx.x == 0) {
        int deg = s[0] + s[1] + s[2] + s[3];
        dinv[n] = deg > 0 ? rsqrtf((float)deg) : 0.0f;
    }
}

// ---------------- bitmask -> compact neighbor list (idx + folded weight) ----------------
__global__ __launch_bounds__(256) void build_nbrs(const unsigned* __restrict__ adj,
                                                  const float* __restrict__ dinv,
                                                  int* __restrict__ nbr_idx,
                                                  float* __restrict__ nbr_w,
                                                  int* __restrict__ degs) {
    const int r = blockIdx.x;
    const int t = threadIdx.x;
    unsigned m = adj[r * ADJ_WORDS + t];
    int cnt = __popc(m);
    __shared__ int pre[256];
    pre[t] = cnt;
    __syncthreads();
    // Hillis-Steele inclusive prefix sum
    for (int off = 1; off < 256; off <<= 1) {
        int v = (t >= off) ? pre[t - off] : 0;
        __syncthreads();
        pre[t] += v;
        __syncthreads();
    }
    int base = pre[t] - cnt;           // exclusive
    const float dr = dinv[r];
    int* oi = nbr_idx + (size_t)r * MAX_DEG;
    float* ow = nbr_w + (size_t)r * MAX_DEG;
    while (m) {
        int b = __ffs(m) - 1;
        m &= m - 1;
        int c = (t << 5) + b;
        if (base < MAX_DEG) {
            oi[base] = c;
            ow[base] = dr * dinv[c];
        }
        base++;
    }
    if (t == 255) degs[r] = pre[255] < MAX_DEG ? pre[255] : MAX_DEG;
}

// ---------------- H = X @ W^T + b   (fp32, 64x64 tile, 4x4 micro) ----------------
__global__ __launch_bounds__(256) void gemm_bias(const float* __restrict__ X,
                                                 const float* __restrict__ W,
                                                 const float* __restrict__ bias,
                                                 float* __restrict__ H) {
    __shared__ float Xs[16][65];
    __shared__ float Ws[16][65];
    const int bm = blockIdx.y * 64, bn = blockIdx.x * 64;
    const int tid = threadIdx.x;
    const int tx = tid & 15, ty = tid >> 4;
    float acc[4][4] = {};
    for (int k0 = 0; k0 < D; k0 += 16) {
        #pragma unroll
        for (int i = 0; i < 4; i++) {
            int e = tid + 256 * i;
            int row = e >> 4, kk = e & 15;
            Xs[kk][row] = X[(size_t)(bm + row) * D + k0 + kk];
            Ws[kk][row] = W[(size_t)(bn + row) * D + k0 + kk];
        }
        __syncthreads();
        #pragma unroll
        for (int kk = 0; kk < 16; kk++) {
            float a[4], b[4];
            #pragma unroll
            for (int i = 0; i < 4; i++) a[i] = Xs[kk][ty * 4 + i];
            #pragma unroll
            for (int j = 0; j < 4; j++) b[j] = Ws[kk][tx * 4 + j];
            #pragma unroll
            for (int i = 0; i < 4; i++)
                #pragma unroll
                for (int j = 0; j < 4; j++)
                    acc[i][j] += a[i] * b[j];
        }
        __syncthreads();
    }
    #pragma unroll
    for (int i = 0; i < 4; i++) {
        int m = bm + ty * 4 + i;
        #pragma unroll
        for (int j = 0; j < 4; j++) {
            int n = bn + tx * 4 + j;
            H[(size_t)m * D + n] = acc[i][j] + bias[n];
        }
    }
}

// ------- Out[r,:] = sum_j w[r][j] * H[nbr[r][j], :]  — one wave per row, float4 lanes -------
__global__ __launch_bounds__(256) void aggregate2(const int* __restrict__ nbr_idx,
                                                  const float* __restrict__ nbr_w,
                                                  const int* __restrict__ degs,
                                                  const float* __restrict__ H,
                                                  float* __restrict__ Out) {
    const int wave = threadIdx.x >> 6;
    const int lane = threadIdx.x & 63;
    const int r = blockIdx.x * 4 + wave;
    const int deg = degs[r];
    const int* idx = nbr_idx + (size_t)r * MAX_DEG;
    const float* wt = nbr_w + (size_t)r * MAX_DEG;
    const int ch = lane * 4;   // this lane's 4 channels

    float4 acc = make_float4(0.f, 0.f, 0.f, 0.f);
    int j = 0;
    for (; j + 4 <= deg; j += 4) {
        int4 c4 = *(const int4*)(idx + j);
        float4 w4 = *(const float4*)(wt + j);
        float4 v0 = *(const float4*)(H + (size_t)c4.x * D + ch);
        float4 v1 = *(const float4*)(H + (size_t)c4.y * D + ch);
        float4 v2 = *(const float4*)(H + (size_t)c4.z * D + ch);
        float4 v3 = *(const float4*)(H + (size_t)c4.w * D + ch);
        acc.x = fmaf(w4.x, v0.x, acc.x); acc.y = fmaf(w4.x, v0.y, acc.y);
        acc.z = fmaf(w4.x, v0.z, acc.z); acc.w = fmaf(w4.x, v0.w, acc.w);
        acc.x = fmaf(w4.y, v1.x, acc.x); acc.y = fmaf(w4.y, v1.y, acc.y);
        acc.z = fmaf(w4.y, v1.z, acc.z); acc.w = fmaf(w4.y, v1.w, acc.w);
        acc.x = fmaf(w4.z, v2.x, acc.x); acc.y = fmaf(w4.z, v2.y, acc.y);
        acc.z = fmaf(w4.z, v2.z, acc.z); acc.w = fmaf(w4.z, v2.w, acc.w);
        acc.x = fmaf(w4.w, v3.x, acc.x); acc.y = fmaf(w4.w, v3.y, acc.y);
        acc.z = fmaf(w4.w, v3.z, acc.z); acc.w = fmaf(w4.w, v3.w, acc.w);
    }
    for (; j < deg; j++) {
        int c = idx[j];
        float w = wt[j];
        float4 v = *(const float4*)(H + (size_t)c * D + ch);
        acc.x = fmaf(w, v.x, acc.x); acc.y = fmaf(w, v.y, acc.y);
        acc.z = fmaf(w, v.z, acc.z); acc.w = fmaf(w, v.w, acc.w);
    }
    *(float4*)(Out + (size_t)r * D + ch) = acc;
}

// ---------------- BN stats: stage 1 (partials) ----------------
__global__ __launch_bounds__(256) void bn_stats1(const float* __restrict__ H,
                                                 float* __restrict__ psum,
                                                 float* __restrict__ psumsq) {
    const int d = threadIdx.x;
    float s = 0.0f, ss = 0.0f;
    for (int r = blockIdx.x; r < N_NODES; r += gridDim.x) {
        float v = H[(size_t)r * D + d];
        s += v;
        ss += v * v;
    }
    psum[blockIdx.x * D + d] = s;
    psumsq[blockIdx.x * D + d] = ss;
}

// ---------------- BN stats: stage 2 (finalize scale/shift) ----------------
__global__ __launch_bounds__(256) void bn_stats2(const float* __restrict__ psum,
                                                 const float* __restrict__ psumsq,
                                                 const float* __restrict__ g,
                                                 const float* __restrict__ be,
                                                 float* __restrict__ scale,
                                                 float* __restrict__ shift) {
    const int d = threadIdx.x;
    float s = 0.0f, ss = 0.0f;
    for (int i = 0; i < STATS_BLOCKS; i++) {
        s += psum[i * D + d];
        ss += psumsq[i * D + d];
    }
    float mu = s * (1.0f / N_NODES);
    float var = ss * (1.0f / N_NODES) - mu * mu;
    float rstd = rsqrtf(var + 1e-5f);
    float sc = g[d] * rstd;
    scale[d] = sc;
    shift[d] = be[d] - mu * sc;
}

// ---------------- BN apply (+ optional ReLU) ----------------
template <bool RELU>
__global__ __launch_bounds__(256) void bn_apply(const float* __restrict__ H,
                                                const float* __restrict__ scale,
                                                const float* __restrict__ shift,
                                                float* __restrict__ Out) {
    int i = blockIdx.x * blockDim.x + threadIdx.x;
    int d = i & (D - 1);
    float v = fmaf(H[i], scale[d], shift[d]);
    if (RELU) v = fmaxf(v, 0.0f);
    Out[i] = v;
}

extern "C" void kernel_launch(void* const* d_in, const int* in_sizes, int n_in,
                              void* d_out, int out_size, void* d_ws, size_t ws_size,
                              hipStream_t stream) {
    const float* x  = (const float*)d_in[0];
    const int*   ei = (const int*)d_in[1];
    const float* W1 = (const float*)d_in[2];
    const float* b1 = (const float*)d_in[3];
    const float* W2 = (const float*)d_in[4];
    const float* b2 = (const float*)d_in[5];
    const float* W3 = (const float*)d_in[6];
    const float* b3 = (const float*)d_in[7];
    const float* g1 = (const float*)d_in[8];
    const float* be1 = (const float*)d_in[9];
    const float* g2 = (const float*)d_in[10];
    const float* be2 = (const float*)d_in[11];
    const float* g3 = (const float*)d_in[12];
    const float* be3 = (const float*)d_in[13];

    char* ws = (char*)d_ws;
    // region 0: adj (8 MB) is dead after build_nbrs -> reused as bufA
    unsigned* adj    = (unsigned*)ws;
    float*    bufA   = (float*)ws;
    float*    dinv   = (float*)(ws + (8 << 20));                    // 32 KB
    int*      degs   = (int*)  (ws + (8 << 20) + (32 << 10));       // 32 KB
    float*    scale  = (float*)(ws + (8 << 20) + (64 << 10));       // 1 KB
    float*    shift  = (float*)(ws + (8 << 20) + (68 << 10));       // 1 KB
    float*    psum   = (float*)(ws + (8 << 20) + (128 << 10));      // 256 KB
    float*    psumsq = (float*)(ws + (8 << 20) + (384 << 10));      // 256 KB
    int*      nbr_idx= (int*)  (ws + (9 << 20));                    // 4 MB
    float*    nbr_w  = (float*)(ws + (13 << 20));                   // 4 MB
    float*    bufB   = (float*)(ws + (17 << 20));                   // 8 MB

    hipMemsetAsync(adj, 0, (size_t)N_NODES * ADJ_WORDS * sizeof(unsigned), stream);
    {
        int total = N_EDGES + N_NODES;
        build_adj<<<(total + 255) / 256, 256, 0, stream>>>(ei, adj);
    }
    compute_dinv<<<N_NODES, 256, 0, stream>>>(adj, dinv);
    build_nbrs<<<N_NODES, 256, 0, stream>>>(adj, dinv, nbr_idx, nbr_w, degs);

    dim3 ggrid(D / 64, N_NODES / 64);

    // ---- Layer 1: x -> bufA (gemm) -> bufB (agg) -> bufA (bn+relu)
    gemm_bias<<<ggrid, 256, 0, stream>>>(x, W1, b1, bufA);
    aggregate2<<<N_NODES / 4, 256, 0, stream>>>(nbr_idx, nbr_w, degs, bufA, bufB);
    bn_stats1<<<STATS_BLOCKS, 256, 0, stream>>>(bufB, psum, psumsq);
    bn_stats2<<<1, 256, 0, stream>>>(psum, psumsq, g1, be1, scale, shift);
    bn_apply<true><<<N_NODES * D / 256, 256, 0, stream>>>(bufB, scale, shift, bufA);

    // ---- Layer 2: bufA -> bufB (gemm) -> bufA (agg) -> bufB (bn+relu)
    gemm_bias<<<ggrid, 256, 0, stream>>>(bufA, W2, b2, bufB);
    aggregate2<<<N_NODES / 4, 256, 0, stream>>>(nbr_idx, nbr_w, degs, bufB, bufA);
    bn_stats1<<<STATS_BLOCKS, 256, 0, stream>>>(bufA, psum, psumsq);
    bn_stats2<<<1, 256, 0, stream>>>(psum, psumsq, g2, be2, scale, shift);
    bn_apply<true><<<N_NODES * D / 256, 256, 0, stream>>>(bufA, scale, shift, bufB);

    // ---- Layer 3: bufB -> bufA (gemm) -> bufB (agg) -> d_out (bn, no relu)
    gemm_bias<<<ggrid, 256, 0, stream>>>(bufB, W3, b3, bufA);
    aggregate2<<<N_NODES / 4, 256, 0, stream>>>(nbr_idx, nbr_w, degs, bufA, bufB);
    bn_stats1<<<STATS_BLOCKS, 256, 0, stream>>>(bufB, psum, psumsq);
    bn_stats2<<<1, 256, 0, stream>>>(psum, psumsq, g3, be3, scale, shift);
    bn_apply<false><<<N_NODES * D / 256, 256, 0, stream>>>(bufB, scale, shift, (float*)d_out);
}

// Round 3
// 320.705 us; speedup vs baseline: 1.9460x; 1.0736x over previous
//
#include <hip/hip_runtime.h>

#define N_NODES 8192
#define N_EDGES 262144
#define D 256
#define ADJ_WORDS 256     // 8192 bits per row / 32
#define MAX_DEG 128       // Poisson(33): P(deg>128) ~ 1e-40
#define AGG_BLOCKS 512    // aggregate grid; 4 waves/block, 4 rows/wave

typedef __attribute__((ext_vector_type(8))) short bf16x8;
typedef __attribute__((ext_vector_type(4))) float f32x4;

__device__ __forceinline__ short f2bf(float f) {
    unsigned u = __builtin_bit_cast(unsigned, f);
    u += 0x7fffu + ((u >> 16) & 1);   // round to nearest even
    return (short)(u >> 16);
}
__device__ __forceinline__ float bf2f(unsigned short u) {
    return __builtin_bit_cast(float, ((unsigned)u) << 16);
}

// ---------------- adjacency build: set-semantics via bitmask ----------------
__global__ void build_adj(const int* __restrict__ ei, unsigned* __restrict__ adj) {
    int i = blockIdx.x * blockDim.x + threadIdx.x;
    int r, c;
    if (i < N_EDGES) {
        r = ei[i];
        c = ei[N_EDGES + i];
    } else if (i < N_EDGES + N_NODES) {
        r = i - N_EDGES;          // self loop
        c = r;
    } else {
        return;
    }
    atomicOr(&adj[r * ADJ_WORDS + (c >> 5)], 1u << (c & 31));
}

// ---------------- degree -> dinv = deg^-0.5 ----------------
__global__ __launch_bounds__(256) void compute_dinv(const unsigned* __restrict__ adj,
                                                    float* __restrict__ dinv) {
    int n = blockIdx.x;
    int cnt = __popc(adj[n * ADJ_WORDS + threadIdx.x]);
    for (int off = 32; off; off >>= 1) cnt += __shfl_down(cnt, off, 64);
    __shared__ int s[4];
    if ((threadIdx.x & 63) == 0) s[threadIdx.x >> 6] = cnt;
    __syncthreads();
    if (threadIdx.x == 0) {
        int deg = s[0] + s[1] + s[2] + s[3];
        dinv[n] = deg > 0 ? rsqrtf((float)deg) : 0.0f;
    }
}

// ---------------- bitmask -> compact neighbor list (shfl-scan, 1 barrier) ----------------
__global__ __launch_bounds__(256) void build_nbrs(const unsigned* __restrict__ adj,
                                                  const float* __restrict__ dinv,
                                                  int* __restrict__ nbr_idx,
                                                  float* __restrict__ nbr_w,
                                                  int* __restrict__ degs) {
    const int r = blockIdx.x;
    const int t = threadIdx.x;
    const int lane = t & 63, wave = t >> 6;
    unsigned m = adj[r * ADJ_WORDS + t];
    int cnt = __popc(m);
    int x = cnt;
    #pragma unroll
    for (int off = 1; off < 64; off <<= 1) {
        int v = __shfl_up(x, off, 64);
        if (lane >= off) x += v;
    }
    __shared__ int wtot[4];
    if (lane == 63) wtot[wave] = x;
    __syncthreads();
    int woff = 0;
    #pragma unroll
    for (int w = 0; w < 4; w++) woff += (w < wave) ? wtot[w] : 0;
    int base = woff + x - cnt;       // exclusive prefix
    const float dr = dinv[r];
    int* oi = nbr_idx + (size_t)r * MAX_DEG;
    float* ow = nbr_w + (size_t)r * MAX_DEG;
    while (m) {
        int b = __ffs(m) - 1;
        m &= m - 1;
        int c = (t << 5) + b;
        if (base < MAX_DEG) {
            oi[base] = c;
            ow[base] = dr * dinv[c];
        }
        base++;
    }
    if (t == 255) {
        int tot = woff + x;
        degs[r] = tot < MAX_DEG ? tot : MAX_DEG;
    }
}

// ---------------- W fp32 -> bf16 (all three layers, one dispatch) ----------------
__global__ __launch_bounds__(256) void convert_weights(const float* __restrict__ W1,
                                                       const float* __restrict__ W2,
                                                       const float* __restrict__ W3,
                                                       unsigned short* __restrict__ Wb1,
                                                       unsigned short* __restrict__ Wb2,
                                                       unsigned short* __restrict__ Wb3) {
    int i = blockIdx.x * 256 + threadIdx.x;
    int which = i >> 16, j = i & 65535;
    const float* src = which == 0 ? W1 : which == 1 ? W2 : W3;
    unsigned short* dst = which == 0 ? Wb1 : which == 1 ? Wb2 : Wb3;
    dst[j] = (unsigned short)f2bf(src[j]);
}

// ---------------- H(bf16) = bnapply(Xsrc) @ W^T + b  (MFMA 16x16x32 bf16) ----------------
// A = W (n rows), B = X (m cols): D[n][m]. C/D layout: col(lane&15)=m, row(q*4+reg)=n
// so the 4 acc regs are consecutive output channels -> 8B packed bf16 store.
template <bool APPLY, bool RELU>
__global__ __launch_bounds__(256) void gemm_mfma(const float* __restrict__ Xsrc,
                                                 const float* __restrict__ scale,
                                                 const float* __restrict__ shift,
                                                 const unsigned short* __restrict__ Wb,
                                                 const float* __restrict__ bias,
                                                 unsigned short* __restrict__ Hb) {
    const int bn = blockIdx.x * 64;           // output-channel tile
    const int bm = blockIdx.y * 128;          // node tile
    const int tid = threadIdx.x;
    const int wave = tid >> 6, lane = tid & 63;
    const int l16 = lane & 15, q = lane >> 4;
    const int mrow0 = bm + wave * 32;         // this wave: 32 nodes x 64 channels

    f32x4 acc[2][4];
    #pragma unroll
    for (int i = 0; i < 2; i++)
        #pragma unroll
        for (int j = 0; j < 4; j++) acc[i][j] = (f32x4){0.f, 0.f, 0.f, 0.f};

    for (int k0 = 0; k0 < D; k0 += 32) {
        const int kq = k0 + q * 8;
        // X fragments (operand B): 8 fp32 -> (bn-apply) -> bf16
        bf16x8 xb[2];
        float4 sc0, sc1, sh0, sh1;
        if (APPLY) {
            sc0 = *(const float4*)(scale + kq);
            sc1 = *(const float4*)(scale + kq + 4);
            sh0 = *(const float4*)(shift + kq);
            sh1 = *(const float4*)(shift + kq + 4);
        }
        #pragma unroll
        for (int mf = 0; mf < 2; mf++) {
            const float* xr = Xsrc + (size_t)(mrow0 + mf * 16 + l16) * D + kq;
            float4 a = *(const float4*)xr;
            float4 b = *(const float4*)(xr + 4);
            float v[8] = {a.x, a.y, a.z, a.w, b.x, b.y, b.z, b.w};
            if (APPLY) {
                float sc[8] = {sc0.x, sc0.y, sc0.z, sc0.w, sc1.x, sc1.y, sc1.z, sc1.w};
                float sh[8] = {sh0.x, sh0.y, sh0.z, sh0.w, sh1.x, sh1.y, sh1.z, sh1.w};
                #pragma unroll
                for (int j = 0; j < 8; j++) {
                    v[j] = fmaf(v[j], sc[j], sh[j]);
                    if (RELU) v[j] = fmaxf(v[j], 0.0f);
                }
            }
            #pragma unroll
            for (int j = 0; j < 8; j++) xb[mf][j] = f2bf(v[j]);
        }
        // W fragments (operand A): direct bf16 16B loads
        #pragma unroll
        for (int nf = 0; nf < 4; nf++) {
            bf16x8 wa = *(const bf16x8*)(Wb + (size_t)(bn + nf * 16 + l16) * D + kq);
            #pragma unroll
            for (int mf = 0; mf < 2; mf++)
                acc[mf][nf] = __builtin_amdgcn_mfma_f32_16x16x32_bf16(wa, xb[mf], acc[mf][nf], 0, 0, 0);
        }
    }

    #pragma unroll
    for (int mf = 0; mf < 2; mf++) {
        const int m = mrow0 + mf * 16 + l16;
        #pragma unroll
        for (int nf = 0; nf < 4; nf++) {
            const int nb = bn + nf * 16 + q * 4;
            float4 b4 = *(const float4*)(bias + nb);
            short4 o;
            o.x = f2bf(acc[mf][nf][0] + b4.x);
            o.y = f2bf(acc[mf][nf][1] + b4.y);
            o.z = f2bf(acc[mf][nf][2] + b4.z);
            o.w = f2bf(acc[mf][nf][3] + b4.w);
            *(short4*)(Hb + (size_t)m * D + nb) = o;
        }
    }
}

// ------- G[r,:] = sum_j w[r][j] * Hb[nbr[r][j], :]  + fused BN partial sums -------
__global__ __launch_bounds__(256) void aggregate_bf16(const int* __restrict__ nbr_idx,
                                                      const float* __restrict__ nbr_w,
                                                      const int* __restrict__ degs,
                                                      const unsigned short* __restrict__ Hb,
                                                      float* __restrict__ G,
                                                      float* __restrict__ psum,
                                                      float* __restrict__ psumsq) {
    const int wave = threadIdx.x >> 6;
    const int lane = threadIdx.x & 63;
    const int ch = lane * 4;
    float sp[4] = {0.f, 0.f, 0.f, 0.f}, ssp[4] = {0.f, 0.f, 0.f, 0.f};

    for (int r = blockIdx.x * 4 + wave; r < N_NODES; r += AGG_BLOCKS * 4) {
        const int deg = degs[r];
        const int* idx = nbr_idx + (size_t)r * MAX_DEG;
        const float* wt = nbr_w + (size_t)r * MAX_DEG;
        float4 acc = make_float4(0.f, 0.f, 0.f, 0.f);
        int j = 0;
        for (; j + 4 <= deg; j += 4) {
            int4 c4 = *(const int4*)(idx + j);
            float4 w4 = *(const float4*)(wt + j);
            ushort4 u0 = *(const ushort4*)(Hb + (size_t)c4.x * D + ch);
            ushort4 u1 = *(const ushort4*)(Hb + (size_t)c4.y * D + ch);
            ushort4 u2 = *(const ushort4*)(Hb + (size_t)c4.z * D + ch);
            ushort4 u3 = *(const ushort4*)(Hb + (size_t)c4.w * D + ch);
            acc.x = fmaf(w4.x, bf2f(u0.x), acc.x); acc.y = fmaf(w4.x, bf2f(u0.y), acc.y);
            acc.z = fmaf(w4.x, bf2f(u0.z), acc.z); acc.w = fmaf(w4.x, bf2f(u0.w), acc.w);
            acc.x = fmaf(w4.y, bf2f(u1.x), acc.x); acc.y = fmaf(w4.y, bf2f(u1.y), acc.y);
            acc.z = fmaf(w4.y, bf2f(u1.z), acc.z); acc.w = fmaf(w4.y, bf2f(u1.w), acc.w);
            acc.x = fmaf(w4.z, bf2f(u2.x), acc.x); acc.y = fmaf(w4.z, bf2f(u2.y), acc.y);
            acc.z = fmaf(w4.z, bf2f(u2.z), acc.z); acc.w = fmaf(w4.z, bf2f(u2.w), acc.w);
            acc.x = fmaf(w4.w, bf2f(u3.x), acc.x); acc.y = fmaf(w4.w, bf2f(u3.y), acc.y);
            acc.z = fmaf(w4.w, bf2f(u3.z), acc.z); acc.w = fmaf(w4.w, bf2f(u3.w), acc.w);
        }
        for (; j < deg; j++) {
            int c = idx[j];
            float w = wt[j];
            ushort4 u = *(const ushort4*)(Hb + (size_t)c * D + ch);
            acc.x = fmaf(w, bf2f(u.x), acc.x); acc.y = fmaf(w, bf2f(u.y), acc.y);
            acc.z = fmaf(w, bf2f(u.z), acc.z); acc.w = fmaf(w, bf2f(u.w), acc.w);
        }
        *(float4*)(G + (size_t)r * D + ch) = acc;
        sp[0] += acc.x; sp[1] += acc.y; sp[2] += acc.z; sp[3] += acc.w;
        ssp[0] += acc.x * acc.x; ssp[1] += acc.y * acc.y;
        ssp[2] += acc.z * acc.z; ssp[3] += acc.w * acc.w;
    }

    __shared__ float ls[4][256], lss[4][256];
    #pragma unroll
    for (int c = 0; c < 4; c++) {
        ls[wave][ch + c] = sp[c];
        lss[wave][ch + c] = ssp[c];
    }
    __syncthreads();
    const int t = threadIdx.x;
    psum[blockIdx.x * 256 + t] = ls[0][t] + ls[1][t] + ls[2][t] + ls[3][t];
    psumsq[blockIdx.x * 256 + t] = lss[0][t] + lss[1][t] + lss[2][t] + lss[3][t];
}

// ---------------- BN stats finalize: scale/shift ----------------
__global__ __launch_bounds__(256) void bn_stats2(const float* __restrict__ psum,
                                                 const float* __restrict__ psumsq,
                                                 const float* __restrict__ g,
                                                 const float* __restrict__ be,
                                                 float* __restrict__ scale,
                                                 float* __restrict__ shift) {
    const int d = threadIdx.x;
    float s = 0.0f, ss = 0.0f;
    for (int i = 0; i < AGG_BLOCKS; i++) {
        s += psum[i * 256 + d];
        ss += psumsq[i * 256 + d];
    }
    float mu = s * (1.0f / N_NODES);
    float var = ss * (1.0f / N_NODES) - mu * mu;
    float rstd = rsqrtf(var + 1e-5f);
    float sc = g[d] * rstd;
    scale[d] = sc;
    shift[d] = be[d] - mu * sc;
}

// ---------------- final BN apply -> fp32 d_out (no relu) ----------------
__global__ __launch_bounds__(256) void bn_apply_out(const float* __restrict__ G,
                                                    const float* __restrict__ scale,
                                                    const float* __restrict__ shift,
                                                    float* __restrict__ Out) {
    int i = (blockIdx.x * 256 + threadIdx.x) * 4;
    int d = i & (D - 1);
    float4 v = *(const float4*)(G + i);
    float4 sc = *(const float4*)(scale + d);
    float4 sh = *(const float4*)(shift + d);
    v.x = fmaf(v.x, sc.x, sh.x);
    v.y = fmaf(v.y, sc.y, sh.y);
    v.z = fmaf(v.z, sc.z, sh.z);
    v.w = fmaf(v.w, sc.w, sh.w);
    *(float4*)(Out + i) = v;
}

extern "C" void kernel_launch(void* const* d_in, const int* in_sizes, int n_in,
                              void* d_out, int out_size, void* d_ws, size_t ws_size,
                              hipStream_t stream) {
    const float* x  = (const float*)d_in[0];
    const int*   ei = (const int*)d_in[1];
    const float* W1 = (const float*)d_in[2];
    const float* b1 = (const float*)d_in[3];
    const float* W2 = (const float*)d_in[4];
    const float* b2 = (const float*)d_in[5];
    const float* W3 = (const float*)d_in[6];
    const float* b3 = (const float*)d_in[7];
    const float* g1 = (const float*)d_in[8];
    const float* be1 = (const float*)d_in[9];
    const float* g2 = (const float*)d_in[10];
    const float* be2 = (const float*)d_in[11];
    const float* g3 = (const float*)d_in[12];
    const float* be3 = (const float*)d_in[13];

    char* ws = (char*)d_ws;
    // region 0: adj (8 MB) dead after build_nbrs; reused as Hb (bf16, 4 MB)
    unsigned*       adj   = (unsigned*)ws;
    unsigned short* Hb    = (unsigned short*)ws;
    float*          dinv  = (float*)(ws + (8 << 20));
    int*            degs  = (int*)  (ws + (8 << 20) + (32 << 10));
    float*          scale = (float*)(ws + (8 << 20) + (64 << 10));
    float*          shift = (float*)(ws + (8 << 20) + (68 << 10));
    unsigned short* Wb1   = (unsigned short*)(ws + (8 << 20) + (128 << 10));
    unsigned short* Wb2   = (unsigned short*)(ws + (8 << 20) + (256 << 10));
    unsigned short* Wb3   = (unsigned short*)(ws + (8 << 20) + (384 << 10));
    float*          psum  = (float*)(ws + (9 << 20));               // 512 KB
    float*          psumsq= (float*)(ws + (9 << 20) + (512 << 10)); // 512 KB
    int*            nbr_idx = (int*)  (ws + (12 << 20));            // 4 MB
    float*          nbr_w   = (float*)(ws + (16 << 20));            // 4 MB
    float*          G       = (float*)(ws + (20 << 20));            // 8 MB

    hipMemsetAsync(adj, 0, (size_t)N_NODES * ADJ_WORDS * sizeof(unsigned), stream);
    {
        int total = N_EDGES + N_NODES;
        build_adj<<<(total + 255) / 256, 256, 0, stream>>>(ei, adj);
    }
    compute_dinv<<<N_NODES, 256, 0, stream>>>(adj, dinv);
    build_nbrs<<<N_NODES, 256, 0, stream>>>(adj, dinv, nbr_idx, nbr_w, degs);
    convert_weights<<<768, 256, 0, stream>>>(W1, W2, W3, Wb1, Wb2, Wb3);

    dim3 ggrid(D / 64, N_NODES / 128);

    // ---- Layer 1: x --gemm--> Hb --agg+stats--> G,psum --stats2--> scale/shift
    gemm_mfma<false, false><<<ggrid, 256, 0, stream>>>(x, nullptr, nullptr, Wb1, b1, Hb);
    aggregate_bf16<<<AGG_BLOCKS, 256, 0, stream>>>(nbr_idx, nbr_w, degs, Hb, G, psum, psumsq);
    bn_stats2<<<1, 256, 0, stream>>>(psum, psumsq, g1, be1, scale, shift);

    // ---- Layer 2: bn+relu fused into gemm's X-load
    gemm_mfma<true, true><<<ggrid, 256, 0, stream>>>(G, scale, shift, Wb2, b2, Hb);
    aggregate_bf16<<<AGG_BLOCKS, 256, 0, stream>>>(nbr_idx, nbr_w, degs, Hb, G, psum, psumsq);
    bn_stats2<<<1, 256, 0, stream>>>(psum, psumsq, g2, be2, scale, shift);

    // ---- Layer 3
    gemm_mfma<true, true><<<ggrid, 256, 0, stream>>>(G, scale, shift, Wb3, b3, Hb);
    aggregate_bf16<<<AGG_BLOCKS, 256, 0, stream>>>(nbr_idx, nbr_w, degs, Hb, G, psum, psumsq);
    bn_stats2<<<1, 256, 0, stream>>>(psum, psumsq, g3, be3, scale, shift);

    // ---- final BN apply -> d_out
    bn_apply_out<<<N_NODES * D / 1024, 256, 0, stream>>>(G, scale, shift, (float*)d_out);
}